// Round 2
// baseline (551.291 us; speedup 1.0000x reference)
//
#include <hip/hip_runtime.h>

typedef unsigned short u16;
typedef unsigned int u32;
typedef short bf16x8 __attribute__((ext_vector_type(8)));
typedef float f32x4 __attribute__((ext_vector_type(4)));

__device__ __forceinline__ u16 f2bf(float f) {
  union { float f; u32 i; } v; v.f = f;
  u32 x = v.i;
  x += 0x7fff + ((x >> 16) & 1);   // RNE
  return (u16)(x >> 16);
}
__device__ __forceinline__ u32 pack2(float a, float b) {
  return (u32)f2bf(a) | ((u32)f2bf(b) << 16);
}

// ---------------- kernel 0: rpb bias gather: bias[h][row*64+col] (f32) ----------------
__global__ void bias_kernel(const float* __restrict__ rpb, const int* __restrict__ rel,
                            float* __restrict__ bias) {
  int idx = blockIdx.x * 256 + threadIdx.x;
  if (idx < 4 * 4096) {
    int h = idx >> 12, rm = idx & 4095;
    bias[idx] = rpb[rel[rm] * 4 + h];
  }
}

// ---------------- kernel 1: LN1 + shifted-window attention + proj + residual ----------------
// one block per window (2048 blocks, 256 threads = 4 waves)
__global__ __launch_bounds__(256, 1) void attn_kernel(
    const float* __restrict__ x, const float* __restrict__ qkv_w,
    const float* __restrict__ proj_w, const float* __restrict__ proj_b,
    const float* __restrict__ n1g, const float* __restrict__ n1b,
    const float* __restrict__ amask, const float* __restrict__ bias,
    float* __restrict__ out)
{
  // LDS arena (bytes). strides padded: 128-wide rows -> 136 elems (272B), 64-wide -> 72 elems.
  __shared__ __align__(16) unsigned char lds[88064];
  __shared__ int srcIdx[64];
  u16* xw = (u16*)(lds);            // [64][136] bf16
  u16* wb = (u16*)(lds + 17408);    // [64][136]
  u16* qb = (u16*)(lds + 34816);    // [64][136]
  u16* kb = (u16*)(lds + 52224);    // [64][136]
  u16* vt = (u16*)(lds + 69632);    // [128][72]  (channel-major V for PV B-operand)
  u16* Pb = (u16*)(lds);            // [4][64][72] = 36864B, overlaps xw+wb (dead then)
  u16* Ob = kb;                     // [64][136]
  u16* pw = vt;                     // [64][136]

  const int tid = threadIdx.x;
  const int wave = tid >> 6, lane = tid & 63;
  const int l15 = lane & 15, lg = lane >> 4;

  const int wIdx = blockIdx.x;
  const int bb = wIdx >> 9, ww = wIdx & 511;
  const int w0 = ww >> 6, w1 = (ww >> 3) & 7, w2 = ww & 7;

  // ---- LN1 + roll-gather into xw ----
  {
    const int tok = wave * 16 + (lane >> 2);
    const int qt = lane & 3;
    const int s0 = tok >> 4, s1 = (tok >> 2) & 3, s2 = tok & 3;
    const int p0 = (w0 * 4 + s0 + 2) & 31;
    const int p1 = (w1 * 4 + s1 + 2) & 31;
    const int p2 = (w2 * 4 + s2 + 2) & 31;
    const int src = (bb << 15) + (p0 << 10) + (p1 << 5) + p2;
    if (qt == 0) srcIdx[tok] = src;
    float v[32]; float s = 0.f, sq = 0.f;
    const float4* p4 = (const float4*)(x + src * 128 + qt * 32);
    #pragma unroll
    for (int i = 0; i < 8; ++i) {
      float4 u = p4[i];
      v[i * 4 + 0] = u.x; v[i * 4 + 1] = u.y; v[i * 4 + 2] = u.z; v[i * 4 + 3] = u.w;
      s += u.x + u.y + u.z + u.w;
      sq += u.x * u.x + u.y * u.y + u.z * u.z + u.w * u.w;
    }
    s  += __shfl_xor(s, 1);  s  += __shfl_xor(s, 2);
    sq += __shfl_xor(sq, 1); sq += __shfl_xor(sq, 2);
    const float mean = s * 0.0078125f;
    const float var  = sq * 0.0078125f - mean * mean;
    const float rstd = rsqrtf(var + 1e-5f);
    u16* dst = xw + tok * 136 + qt * 32;
    #pragma unroll
    for (int i = 0; i < 32; i += 2) {
      const int c = qt * 32 + i;
      float y0 = (v[i]     - mean) * rstd * n1g[c]     + n1b[c];
      float y1 = (v[i + 1] - mean) * rstd * n1g[c + 1] + n1b[c + 1];
      *(u32*)(dst + i) = pack2(y0, y1);
    }
  }
  __syncthreads();

  // ---- QKV: 6 chunks of 64 output cols; K=128 ----
  const float scale = 0.17677669529663687f;  // 32^-0.5
  const f32x4 zero4 = {0.f, 0.f, 0.f, 0.f};
  #pragma unroll 1
  for (int cc = 0; cc < 6; ++cc) {
    {
      const int row = tid >> 2, part = tid & 3;
      const float4* g4 = (const float4*)(qkv_w + (cc * 64 + row) * 128 + part * 32);
      u32* d4 = (u32*)(wb + row * 136 + part * 32);
      #pragma unroll
      for (int i = 0; i < 8; ++i) {
        float4 u = g4[i];
        d4[i * 2]     = pack2(u.x, u.y);
        d4[i * 2 + 1] = pack2(u.z, u.w);
      }
    }
    __syncthreads();
    f32x4 acc[4];
    #pragma unroll
    for (int t = 0; t < 4; ++t) acc[t] = zero4;
    #pragma unroll
    for (int ks = 0; ks < 4; ++ks) {
      const bf16x8 bfr = *(const bf16x8*)(wb + (wave * 16 + l15) * 136 + ks * 32 + lg * 8);
      #pragma unroll
      for (int ti = 0; ti < 4; ++ti) {
        const bf16x8 afr = *(const bf16x8*)(xw + (ti * 16 + l15) * 136 + ks * 32 + lg * 8);
        acc[ti] = __builtin_amdgcn_mfma_f32_16x16x32_bf16(afr, bfr, acc[ti], 0, 0, 0);
      }
    }
    const int o = cc * 64 + wave * 16 + l15;
    #pragma unroll
    for (int ti = 0; ti < 4; ++ti) {
      #pragma unroll
      for (int r = 0; r < 4; ++r) {
        const int tok = ti * 16 + lg * 4 + r;
        const float val = acc[ti][r];
        if (o < 128)      qb[tok * 136 + o] = f2bf(val * scale);
        else if (o < 256) kb[tok * 136 + (o - 128)] = f2bf(val);
        else              vt[(o - 256) * 72 + tok] = f2bf(val);
      }
    }
    __syncthreads();
  }

  // ---- QK^T per head (wave = head), K=32 = head dim ----
  const int h = wave;
  f32x4 s[4][4];
  {
    bf16x8 qa[4];
    #pragma unroll
    for (int ti = 0; ti < 4; ++ti)
      qa[ti] = *(const bf16x8*)(qb + (ti * 16 + l15) * 136 + h * 32 + lg * 8);
    #pragma unroll
    for (int tj = 0; tj < 4; ++tj) {
      const bf16x8 kf = *(const bf16x8*)(kb + (tj * 16 + l15) * 136 + h * 32 + lg * 8);
      #pragma unroll
      for (int ti = 0; ti < 4; ++ti)
        s[ti][tj] = __builtin_amdgcn_mfma_f32_16x16x32_bf16(qa[ti], kf, zero4, 0, 0, 0);
    }
  }
  // bias + shift mask (both f32 tables)
  #pragma unroll
  for (int ti = 0; ti < 4; ++ti) {
    #pragma unroll
    for (int r = 0; r < 4; ++r) {
      const int row = ti * 16 + lg * 4 + r;
      const float* bp = bias + h * 4096 + row * 64;
      const float* mp = amask + ww * 4096 + row * 64;
      #pragma unroll
      for (int tj = 0; tj < 4; ++tj) {
        const int col = tj * 16 + l15;
        s[ti][tj][r] += bp[col] + mp[col];
      }
    }
  }
  __syncthreads();   // all q/k reads done before P overwrites that region

  // ---- softmax (rows live on 16-lane groups matching D layout) + write P ----
  float rcp[4][4];
  #pragma unroll
  for (int ti = 0; ti < 4; ++ti) {
    #pragma unroll
    for (int r = 0; r < 4; ++r) {
      float mx = fmaxf(fmaxf(s[ti][0][r], s[ti][1][r]), fmaxf(s[ti][2][r], s[ti][3][r]));
      mx = fmaxf(mx, __shfl_xor(mx, 1));
      mx = fmaxf(mx, __shfl_xor(mx, 2));
      mx = fmaxf(mx, __shfl_xor(mx, 4));
      mx = fmaxf(mx, __shfl_xor(mx, 8));
      float sum = 0.f;
      #pragma unroll
      for (int tj = 0; tj < 4; ++tj) {
        float e = __expf(s[ti][tj][r] - mx);
        s[ti][tj][r] = e; sum += e;
      }
      sum += __shfl_xor(sum, 1);
      sum += __shfl_xor(sum, 2);
      sum += __shfl_xor(sum, 4);
      sum += __shfl_xor(sum, 8);
      rcp[ti][r] = 1.0f / sum;
      const int row = ti * 16 + lg * 4 + r;
      u16* pp = Pb + (h * 64 + row) * 72;
      #pragma unroll
      for (int tj = 0; tj < 4; ++tj)
        pp[tj * 16 + l15] = f2bf(s[ti][tj][r]);  // unnormalized; 1/sum folded into PV out
    }
  }
  __syncthreads();

  // ---- PV: out_h(64x32) = P(64x64) @ v_h(64x32) ----
  {
    f32x4 oacc[4][2];
    #pragma unroll
    for (int ti = 0; ti < 4; ++ti) { oacc[ti][0] = zero4; oacc[ti][1] = zero4; }
    #pragma unroll
    for (int ks = 0; ks < 2; ++ks) {
      bf16x8 pa[4], vb[2];
      #pragma unroll
      for (int ti = 0; ti < 4; ++ti)
        pa[ti] = *(const bf16x8*)(Pb + (h * 64 + ti * 16 + l15) * 72 + ks * 32 + lg * 8);
      #pragma unroll
      for (int tj = 0; tj < 2; ++tj)
        vb[tj] = *(const bf16x8*)(vt + (h * 32 + tj * 16 + l15) * 72 + ks * 32 + lg * 8);
      #pragma unroll
      for (int ti = 0; ti < 4; ++ti)
        #pragma unroll
        for (int tj = 0; tj < 2; ++tj)
          oacc[ti][tj] = __builtin_amdgcn_mfma_f32_16x16x32_bf16(pa[ti], vb[tj], oacc[ti][tj], 0, 0, 0);
    }
    #pragma unroll
    for (int ti = 0; ti < 4; ++ti)
      #pragma unroll
      for (int tj = 0; tj < 2; ++tj)
        #pragma unroll
        for (int r = 0; r < 4; ++r) {
          const int tok = ti * 16 + lg * 4 + r;
          Ob[tok * 136 + h * 32 + tj * 16 + l15] = f2bf(oacc[ti][tj][r] * rcp[ti][r]);
        }
  }
  __syncthreads();   // O visible; vt reads done before pw staging

  // ---- proj (2 chunks of 64 cols) + residual epilogue (scatter = inverse roll) ----
  #pragma unroll 1
  for (int cc = 0; cc < 2; ++cc) {
    {
      const int row = tid >> 2, part = tid & 3;
      const float4* g4 = (const float4*)(proj_w + (cc * 64 + row) * 128 + part * 32);
      u32* d4 = (u32*)(pw + row * 136 + part * 32);
      #pragma unroll
      for (int i = 0; i < 8; ++i) {
        float4 u = g4[i];
        d4[i * 2]     = pack2(u.x, u.y);
        d4[i * 2 + 1] = pack2(u.z, u.w);
      }
    }
    __syncthreads();
    f32x4 acc[4];
    #pragma unroll
    for (int t = 0; t < 4; ++t) acc[t] = zero4;
    #pragma unroll
    for (int ks = 0; ks < 4; ++ks) {
      const bf16x8 bfr = *(const bf16x8*)(pw + (wave * 16 + l15) * 136 + ks * 32 + lg * 8);
      #pragma unroll
      for (int ti = 0; ti < 4; ++ti) {
        const bf16x8 afr = *(const bf16x8*)(Ob + (ti * 16 + l15) * 136 + ks * 32 + lg * 8);
        acc[ti] = __builtin_amdgcn_mfma_f32_16x16x32_bf16(afr, bfr, acc[ti], 0, 0, 0);
      }
    }
    const int c = cc * 64 + wave * 16 + l15;
    const float pbv = proj_b[c];
    #pragma unroll
    for (int ti = 0; ti < 4; ++ti) {
      #pragma unroll
      for (int r = 0; r < 4; ++r) {
        const int tok = ti * 16 + lg * 4 + r;
        const int src = srcIdx[tok];
        out[src * 128 + c] = x[src * 128 + c] + 0.5f * (acc[ti][r] + pbv);
      }
    }
    __syncthreads();
  }
}

// ---------------- kernel 2: LN2 + MLP + residual (in-place on d_out=x1) ----------------
__global__ __launch_bounds__(256, 1) void mlp_kernel(
    const float* __restrict__ w1, const float* __restrict__ b1,
    const float* __restrict__ w2, const float* __restrict__ b2,
    const float* __restrict__ n2g, const float* __restrict__ n2b,
    float* __restrict__ out)
{
  __shared__ __align__(16) unsigned char lds[101376];
  u16* xn = (u16*)(lds);            // [64][136] bf16
  u16* wb = (u16*)(lds + 17408);    // [64][136]
  u16* h1 = (u16*)(lds + 34816);    // [64][520]

  const int tid = threadIdx.x;
  const int wave = tid >> 6, lane = tid & 63;
  const int l15 = lane & 15, lg = lane >> 4;
  const int base = blockIdx.x * 64;
  const f32x4 zero4 = {0.f, 0.f, 0.f, 0.f};

  // ---- LN2 over x1 (read from out) ----
  {
    const int tl = wave * 16 + (lane >> 2);
    const int qt = lane & 3;
    const int tokg = base + tl;
    float v[32]; float s = 0.f, sq = 0.f;
    const float4* p4 = (const float4*)(out + tokg * 128 + qt * 32);
    #pragma unroll
    for (int i = 0; i < 8; ++i) {
      float4 u = p4[i];
      v[i * 4 + 0] = u.x; v[i * 4 + 1] = u.y; v[i * 4 + 2] = u.z; v[i * 4 + 3] = u.w;
      s += u.x + u.y + u.z + u.w;
      sq += u.x * u.x + u.y * u.y + u.z * u.z + u.w * u.w;
    }
    s  += __shfl_xor(s, 1);  s  += __shfl_xor(s, 2);
    sq += __shfl_xor(sq, 1); sq += __shfl_xor(sq, 2);
    const float mean = s * 0.0078125f;
    const float var  = sq * 0.0078125f - mean * mean;
    const float rstd = rsqrtf(var + 1e-5f);
    u16* dst = xn + tl * 136 + qt * 32;
    #pragma unroll
    for (int i = 0; i < 32; i += 2) {
      const int c = qt * 32 + i;
      float y0 = (v[i]     - mean) * rstd * n2g[c]     + n2b[c];
      float y1 = (v[i + 1] - mean) * rstd * n2g[c + 1] + n2b[c + 1];
      *(u32*)(dst + i) = pack2(y0, y1);
    }
  }
  __syncthreads();

  // ---- h1 = gelu(xn @ w1^T + b1): 8 chunks of 64 cols, K=128 ----
  #pragma unroll 1
  for (int cc = 0; cc < 8; ++cc) {
    {
      const int row = tid >> 2, part = tid & 3;
      const float4* g4 = (const float4*)(w1 + (cc * 64 + row) * 128 + part * 32);
      u32* d4 = (u32*)(wb + row * 136 + part * 32);
      #pragma unroll
      for (int i = 0; i < 8; ++i) {
        float4 u = g4[i];
        d4[i * 2]     = pack2(u.x, u.y);
        d4[i * 2 + 1] = pack2(u.z, u.w);
      }
    }
    __syncthreads();
    f32x4 acc[4];
    #pragma unroll
    for (int t = 0; t < 4; ++t) acc[t] = zero4;
    #pragma unroll
    for (int ks = 0; ks < 4; ++ks) {
      const bf16x8 bfr = *(const bf16x8*)(wb + (wave * 16 + l15) * 136 + ks * 32 + lg * 8);
      #pragma unroll
      for (int ti = 0; ti < 4; ++ti) {
        const bf16x8 afr = *(const bf16x8*)(xn + (ti * 16 + l15) * 136 + ks * 32 + lg * 8);
        acc[ti] = __builtin_amdgcn_mfma_f32_16x16x32_bf16(afr, bfr, acc[ti], 0, 0, 0);
      }
    }
    const int o = cc * 64 + wave * 16 + l15;
    const float bias1 = b1[o];
    #pragma unroll
    for (int ti = 0; ti < 4; ++ti) {
      #pragma unroll
      for (int r = 0; r < 4; ++r) {
        const int tok = ti * 16 + lg * 4 + r;
        const float u = acc[ti][r] + bias1;
        const float ge = 0.5f * u * (1.0f + erff(u * 0.70710678118654752f));
        h1[tok * 520 + o] = f2bf(ge);
      }
    }
    __syncthreads();
  }

  // ---- h2 = h1 @ w2^T + b2 ; out = x1 + 0.5*h2 ----
  #pragma unroll 1
  for (int oc = 0; oc < 2; ++oc) {
    f32x4 acc[4];
    #pragma unroll
    for (int t = 0; t < 4; ++t) acc[t] = zero4;
    #pragma unroll 1
    for (int kc = 0; kc < 4; ++kc) {
      {
        const int row = tid >> 2, part = tid & 3;
        const float4* g4 = (const float4*)(w2 + (oc * 64 + row) * 512 + kc * 128 + part * 32);
        u32* d4 = (u32*)(wb + row * 136 + part * 32);
        #pragma unroll
        for (int i = 0; i < 8; ++i) {
          float4 u = g4[i];
          d4[i * 2]     = pack2(u.x, u.y);
          d4[i * 2 + 1] = pack2(u.z, u.w);
        }
      }
      __syncthreads();
      #pragma unroll
      for (int ks = 0; ks < 4; ++ks) {
        const bf16x8 bfr = *(const bf16x8*)(wb + (wave * 16 + l15) * 136 + ks * 32 + lg * 8);
        #pragma unroll
        for (int ti = 0; ti < 4; ++ti) {
          const bf16x8 afr = *(const bf16x8*)(h1 + (ti * 16 + l15) * 520 + kc * 128 + ks * 32 + lg * 8);
          acc[ti] = __builtin_amdgcn_mfma_f32_16x16x32_bf16(afr, bfr, acc[ti], 0, 0, 0);
        }
      }
      __syncthreads();
    }
    const int c = oc * 64 + wave * 16 + l15;
    const float bias2 = b2[c];
    #pragma unroll
    for (int ti = 0; ti < 4; ++ti) {
      #pragma unroll
      for (int r = 0; r < 4; ++r) {
        const int tokg = base + ti * 16 + lg * 4 + r;
        const float x1 = out[tokg * 128 + c];
        out[tokg * 128 + c] = x1 + 0.5f * (acc[ti][r] + bias2);
      }
    }
  }
}

extern "C" void kernel_launch(void* const* d_in, const int* in_sizes, int n_in,
                              void* d_out, int out_size, void* d_ws, size_t ws_size,
                              hipStream_t stream) {
  const float* x      = (const float*)d_in[0];
  const float* qkv_w  = (const float*)d_in[1];
  const float* rpb    = (const float*)d_in[2];
  const float* proj_w = (const float*)d_in[3];
  const float* proj_b = (const float*)d_in[4];
  const float* n1g    = (const float*)d_in[5];
  const float* n1b    = (const float*)d_in[6];
  const float* n2g    = (const float*)d_in[7];
  const float* n2b    = (const float*)d_in[8];
  const float* w1     = (const float*)d_in[9];
  const float* b1     = (const float*)d_in[10];
  const float* w2     = (const float*)d_in[11];
  const float* b2     = (const float*)d_in[12];
  const float* amask  = (const float*)d_in[13];
  const int*   rel    = (const int*)d_in[14];
  float* out  = (float*)d_out;
  float* bias = (float*)d_ws;   // 4*4096 floats = 64KB

  bias_kernel<<<64, 256, 0, stream>>>(rpb, rel, bias);
  attn_kernel<<<2048, 256, 0, stream>>>(x, qkv_w, proj_w, proj_b, n1g, n1b, amask, bias, out);
  mlp_kernel<<<2048, 256, 0, stream>>>(w1, b1, w2, b2, n2g, n2b, out);
}

// Round 3
// 252.921 us; speedup vs baseline: 2.1797x; 2.1797x over previous
//
#include <hip/hip_runtime.h>

typedef unsigned short u16;
typedef unsigned int u32;
typedef short bf16x8 __attribute__((ext_vector_type(8)));
typedef float f32x4 __attribute__((ext_vector_type(4)));

__device__ __forceinline__ u16 f2bf(float f) {
  union { float f; u32 i; } v; v.f = f;
  u32 x = v.i;
  x += 0x7fff + ((x >> 16) & 1);   // RNE
  return (u16)(x >> 16);
}
__device__ __forceinline__ u32 pack2(float a, float b) {
  return (u32)f2bf(a) | ((u32)f2bf(b) << 16);
}

// ws layout (bytes):
//   bias  f32 [0, 65536)
//   qkv_p bf16 [65536, 163840)    (384x128, q-rows pre-scaled)
//   proj_p bf16 [163840, 196608)  (128x128)
//   w1p   bf16 [196608, 327680)   (512x128)
//   w2p   bf16 [327680, 458752)   (128x512)

// ---------------- kernel 0a: rpb bias gather ----------------
__global__ void bias_kernel(const float* __restrict__ rpb, const int* __restrict__ rel,
                            float* __restrict__ bias) {
  int idx = blockIdx.x * 256 + threadIdx.x;
  if (idx < 4 * 4096) {
    int h = idx >> 12, rm = idx & 4095;
    bias[idx] = rpb[rel[rm] * 4 + h];
  }
}

// ---------------- kernel 0b: weight pack to bf16 ----------------
__global__ void pack_kernel(const float* __restrict__ qkv_w, const float* __restrict__ proj_w,
                            const float* __restrict__ w1, const float* __restrict__ w2,
                            u16* __restrict__ qkv_p, u16* __restrict__ proj_p,
                            u16* __restrict__ w1p, u16* __restrict__ w2p) {
  const int idx = blockIdx.x * 256 + threadIdx.x;  // 768 blocks -> 196608
  const float scale = 0.17677669529663687f;        // 32^-0.5
  if (idx < 49152) {
    float v = qkv_w[idx];
    if (idx < 16384) v *= scale;                   // fold q-scale into Wq
    qkv_p[idx] = f2bf(v);
  } else if (idx < 65536) {
    proj_p[idx - 49152] = f2bf(proj_w[idx - 49152]);
  } else if (idx < 131072) {
    w1p[idx - 65536] = f2bf(w1[idx - 65536]);
  } else {
    w2p[idx - 131072] = f2bf(w2[idx - 131072]);
  }
}

// ---------------- kernel 1: LN1 + shifted-window attention + proj + residual ----------------
// one block per window (2048 blocks, 512 threads = 8 waves: wave = (half, head))
__global__ __launch_bounds__(512, 2) void attn_kernel(
    const float* __restrict__ x, const u16* __restrict__ qkv_p,
    const u16* __restrict__ proj_p, const float* __restrict__ proj_b,
    const float* __restrict__ n1g, const float* __restrict__ n1b,
    const float* __restrict__ amask, const float* __restrict__ bias,
    float* __restrict__ out)
{
  __shared__ __align__(16) unsigned char lds[88064];
  __shared__ int srcIdx[64];
  u16* xw = (u16*)(lds);            // [64][136] bf16
  u16* wb = (u16*)(lds + 17408);    // [64][136] weight staging
  u16* qb = (u16*)(lds + 34816);    // [64][136]
  u16* kb = (u16*)(lds + 52224);    // [64][136]
  u16* vt = (u16*)(lds + 69632);    // [128][72] channel-major V
  u16* Pb = (u16*)(lds);            // [4][64][72] = 36864B over xw+wb+2KB of qb (dead)
  u16* Ob = kb;                     // [64][136]
  u16* pw = vt;                     // [64][136]

  const int tid = threadIdx.x;
  const int wave = tid >> 6, lane = tid & 63;
  const int l15 = lane & 15, lg = lane >> 4;
  const int hw = wave & 3;          // head / col-group
  const int half = wave >> 2;       // token half (0: toks 0..31, 1: 32..63)

  const int wIdx = blockIdx.x;
  const int bb = wIdx >> 9, ww = wIdx & 511;
  const int w0 = ww >> 6, w1i = (ww >> 3) & 7, w2i = ww & 7;

  // ---- LN1 + roll-gather into xw (8 threads per token) ----
  {
    const int tok = tid >> 3;
    const int qt = tid & 7;
    const int s0 = tok >> 4, s1 = (tok >> 2) & 3, s2 = tok & 3;
    const int p0 = (w0 * 4 + s0 + 2) & 31;
    const int p1 = (w1i * 4 + s1 + 2) & 31;
    const int p2 = (w2i * 4 + s2 + 2) & 31;
    const int src = (bb << 15) + (p0 << 10) + (p1 << 5) + p2;
    if (qt == 0) srcIdx[tok] = src;
    float v[16]; float s = 0.f, sq = 0.f;
    const float4* p4 = (const float4*)(x + src * 128 + qt * 16);
    #pragma unroll
    for (int i = 0; i < 4; ++i) {
      float4 u = p4[i];
      v[i * 4 + 0] = u.x; v[i * 4 + 1] = u.y; v[i * 4 + 2] = u.z; v[i * 4 + 3] = u.w;
      s += u.x + u.y + u.z + u.w;
      sq += u.x * u.x + u.y * u.y + u.z * u.z + u.w * u.w;
    }
    s  += __shfl_xor(s, 1);  s  += __shfl_xor(s, 2);  s  += __shfl_xor(s, 4);
    sq += __shfl_xor(sq, 1); sq += __shfl_xor(sq, 2); sq += __shfl_xor(sq, 4);
    const float mean = s * 0.0078125f;
    const float var  = sq * 0.0078125f - mean * mean;
    const float rstd = rsqrtf(var + 1e-5f);
    u16* dst = xw + tok * 136 + qt * 16;
    #pragma unroll
    for (int i = 0; i < 16; i += 2) {
      const int c = qt * 16 + i;
      float y0 = (v[i]     - mean) * rstd * n1g[c]     + n1b[c];
      float y1 = (v[i + 1] - mean) * rstd * n1g[c + 1] + n1b[c + 1];
      *(u32*)(dst + i) = pack2(y0, y1);
    }
  }
  __syncthreads();

  const f32x4 zero4 = {0.f, 0.f, 0.f, 0.f};

  // ---- QKV: 6 chunks of 64 output cols; K=128 ----
  #pragma unroll 1
  for (int cc = 0; cc < 6; ++cc) {
    {
      const int row = tid >> 3, part = tid & 7;     // 64 rows x 8 parts x 16 elems
      const uint4* g4 = (const uint4*)(qkv_p + (cc * 64 + row) * 128 + part * 16);
      uint4* d4 = (uint4*)(wb + row * 136 + part * 16);
      d4[0] = g4[0]; d4[1] = g4[1];
    }
    __syncthreads();
    f32x4 acc[2] = {zero4, zero4};
    #pragma unroll
    for (int ks = 0; ks < 4; ++ks) {
      const bf16x8 bfr = *(const bf16x8*)(wb + (hw * 16 + l15) * 136 + ks * 32 + lg * 8);
      #pragma unroll
      for (int ti = 0; ti < 2; ++ti) {
        const bf16x8 afr = *(const bf16x8*)(xw + ((half * 2 + ti) * 16 + l15) * 136 + ks * 32 + lg * 8);
        acc[ti] = __builtin_amdgcn_mfma_f32_16x16x32_bf16(afr, bfr, acc[ti], 0, 0, 0);
      }
    }
    const int o = cc * 64 + hw * 16 + l15;
    #pragma unroll
    for (int ti = 0; ti < 2; ++ti) {
      #pragma unroll
      for (int r = 0; r < 4; ++r) {
        const int tok = (half * 2 + ti) * 16 + lg * 4 + r;
        const float val = acc[ti][r];
        if (o < 128)      qb[tok * 136 + o] = f2bf(val);   // scale pre-folded
        else if (o < 256) kb[tok * 136 + (o - 128)] = f2bf(val);
        else              vt[(o - 256) * 72 + tok] = f2bf(val);
      }
    }
    __syncthreads();
  }

  // ---- QK^T (wave = (half, head)), K=32 ----
  f32x4 s[2][4];
  {
    bf16x8 qa[2];
    #pragma unroll
    for (int ti = 0; ti < 2; ++ti)
      qa[ti] = *(const bf16x8*)(qb + ((half * 2 + ti) * 16 + l15) * 136 + hw * 32 + lg * 8);
    #pragma unroll
    for (int tj = 0; tj < 4; ++tj) {
      const bf16x8 kf = *(const bf16x8*)(kb + (tj * 16 + l15) * 136 + hw * 32 + lg * 8);
      #pragma unroll
      for (int ti = 0; ti < 2; ++ti)
        s[ti][tj] = __builtin_amdgcn_mfma_f32_16x16x32_bf16(qa[ti], kf, zero4, 0, 0, 0);
    }
  }
  // bias + shift mask
  #pragma unroll
  for (int ti = 0; ti < 2; ++ti) {
    #pragma unroll
    for (int r = 0; r < 4; ++r) {
      const int row = (half * 2 + ti) * 16 + lg * 4 + r;
      const float* bp = bias + hw * 4096 + row * 64;
      const float* mp = amask + ww * 4096 + row * 64;
      #pragma unroll
      for (int tj = 0; tj < 4; ++tj) {
        const int col = tj * 16 + l15;
        s[ti][tj][r] += bp[col] + mp[col];
      }
    }
  }
  __syncthreads();   // all q/k/xw/wb LDS reads done before P overwrites

  // ---- softmax + P write (each wave writes only rows it will read) ----
  float rcp[2][4];
  #pragma unroll
  for (int ti = 0; ti < 2; ++ti) {
    #pragma unroll
    for (int r = 0; r < 4; ++r) {
      float mx = fmaxf(fmaxf(s[ti][0][r], s[ti][1][r]), fmaxf(s[ti][2][r], s[ti][3][r]));
      mx = fmaxf(mx, __shfl_xor(mx, 1));
      mx = fmaxf(mx, __shfl_xor(mx, 2));
      mx = fmaxf(mx, __shfl_xor(mx, 4));
      mx = fmaxf(mx, __shfl_xor(mx, 8));
      float sum = 0.f;
      #pragma unroll
      for (int tj = 0; tj < 4; ++tj) {
        float e = __expf(s[ti][tj][r] - mx);
        s[ti][tj][r] = e; sum += e;
      }
      sum += __shfl_xor(sum, 1);
      sum += __shfl_xor(sum, 2);
      sum += __shfl_xor(sum, 4);
      sum += __shfl_xor(sum, 8);
      rcp[ti][r] = 1.0f / sum;
      const int row = (half * 2 + ti) * 16 + lg * 4 + r;
      u16* pp = Pb + (hw * 64 + row) * 72;
      #pragma unroll
      for (int tj = 0; tj < 4; ++tj)
        pp[tj * 16 + l15] = f2bf(s[ti][tj][r]);  // unnormalized; 1/sum folded at O write
    }
  }
  // no barrier: each wave reads back only its own P rows

  // ---- PV ----
  {
    f32x4 oacc[2][2] = {{zero4, zero4}, {zero4, zero4}};
    #pragma unroll
    for (int ks = 0; ks < 2; ++ks) {
      bf16x8 pa[2], vb[2];
      #pragma unroll
      for (int ti = 0; ti < 2; ++ti)
        pa[ti] = *(const bf16x8*)(Pb + (hw * 64 + (half * 2 + ti) * 16 + l15) * 72 + ks * 32 + lg * 8);
      #pragma unroll
      for (int tj = 0; tj < 2; ++tj)
        vb[tj] = *(const bf16x8*)(vt + (hw * 32 + tj * 16 + l15) * 72 + ks * 32 + lg * 8);
      #pragma unroll
      for (int ti = 0; ti < 2; ++ti)
        #pragma unroll
        for (int tj = 0; tj < 2; ++tj)
          oacc[ti][tj] = __builtin_amdgcn_mfma_f32_16x16x32_bf16(pa[ti], vb[tj], oacc[ti][tj], 0, 0, 0);
    }
    #pragma unroll
    for (int ti = 0; ti < 2; ++ti)
      #pragma unroll
      for (int tj = 0; tj < 2; ++tj)
        #pragma unroll
        for (int r = 0; r < 4; ++r) {
          const int tok = (half * 2 + ti) * 16 + lg * 4 + r;
          Ob[tok * 136 + hw * 32 + tj * 16 + l15] = f2bf(oacc[ti][tj][r] * rcp[ti][r]);
        }
  }
  __syncthreads();   // O visible to all; vt reads done before pw staging

  // ---- proj (2 chunks of 64 cols) + residual epilogue ----
  #pragma unroll 1
  for (int cc = 0; cc < 2; ++cc) {
    {
      const int row = tid >> 3, part = tid & 7;
      const uint4* g4 = (const uint4*)(proj_p + (cc * 64 + row) * 128 + part * 16);
      uint4* d4 = (uint4*)(pw + row * 136 + part * 16);
      d4[0] = g4[0]; d4[1] = g4[1];
    }
    __syncthreads();
    f32x4 acc[2] = {zero4, zero4};
    #pragma unroll
    for (int ks = 0; ks < 4; ++ks) {
      const bf16x8 bfr = *(const bf16x8*)(pw + (hw * 16 + l15) * 136 + ks * 32 + lg * 8);
      #pragma unroll
      for (int ti = 0; ti < 2; ++ti) {
        const bf16x8 afr = *(const bf16x8*)(Ob + ((half * 2 + ti) * 16 + l15) * 136 + ks * 32 + lg * 8);
        acc[ti] = __builtin_amdgcn_mfma_f32_16x16x32_bf16(afr, bfr, acc[ti], 0, 0, 0);
      }
    }
    const int c = cc * 64 + hw * 16 + l15;
    const float pbv = proj_b[c];
    #pragma unroll
    for (int ti = 0; ti < 2; ++ti) {
      #pragma unroll
      for (int r = 0; r < 4; ++r) {
        const int tok = (half * 2 + ti) * 16 + lg * 4 + r;
        const int src = srcIdx[tok];
        out[src * 128 + c] = x[src * 128 + c] + 0.5f * (acc[ti][r] + pbv);
      }
    }
    __syncthreads();
  }
}

// ---------------- kernel 2: LN2 + MLP + residual (chunked h2, 62.4KB LDS) ----------------
__global__ __launch_bounds__(256, 2) void mlp_kernel(
    const u16* __restrict__ w1p, const float* __restrict__ b1,
    const u16* __restrict__ w2p, const float* __restrict__ b2,
    const float* __restrict__ n2g, const float* __restrict__ n2b,
    float* __restrict__ out)
{
  __shared__ __align__(16) unsigned char lds[62464];
  u16* xn  = (u16*)(lds);           // [64][136] bf16
  u16* w1c = (u16*)(lds + 17408);   // [64][136]  (w1 chunk: 64 o-rows x 128 k)
  u16* w2c = (u16*)(lds + 34816);   // [128][72]  (w2 chunk: 128 c-rows x 64 o)
  u16* h1c = (u16*)(lds + 53248);   // [64][72]   (gelu(h1) chunk)

  const int tid = threadIdx.x;
  const int wave = tid >> 6, lane = tid & 63;
  const int l15 = lane & 15, lg = lane >> 4;
  const int base = blockIdx.x * 64;
  const f32x4 zero4 = {0.f, 0.f, 0.f, 0.f};

  // ---- LN2 over x1 (read from out) ----
  {
    const int tl = tid >> 2;
    const int qt = tid & 3;
    const int tokg = base + tl;
    float v[32]; float s = 0.f, sq = 0.f;
    const float4* p4 = (const float4*)(out + tokg * 128 + qt * 32);
    #pragma unroll
    for (int i = 0; i < 8; ++i) {
      float4 u = p4[i];
      v[i * 4 + 0] = u.x; v[i * 4 + 1] = u.y; v[i * 4 + 2] = u.z; v[i * 4 + 3] = u.w;
      s += u.x + u.y + u.z + u.w;
      sq += u.x * u.x + u.y * u.y + u.z * u.z + u.w * u.w;
    }
    s  += __shfl_xor(s, 1);  s  += __shfl_xor(s, 2);
    sq += __shfl_xor(sq, 1); sq += __shfl_xor(sq, 2);
    const float mean = s * 0.0078125f;
    const float var  = sq * 0.0078125f - mean * mean;
    const float rstd = rsqrtf(var + 1e-5f);
    u16* dst = xn + tl * 136 + qt * 32;
    #pragma unroll
    for (int i = 0; i < 32; i += 2) {
      const int c = qt * 32 + i;
      float y0 = (v[i]     - mean) * rstd * n2g[c]     + n2b[c];
      float y1 = (v[i + 1] - mean) * rstd * n2g[c + 1] + n2b[c + 1];
      *(u32*)(dst + i) = pack2(y0, y1);
    }
  }
  __syncthreads();

  f32x4 acc2[4][2];
  #pragma unroll
  for (int ti = 0; ti < 4; ++ti) { acc2[ti][0] = zero4; acc2[ti][1] = zero4; }

  #pragma unroll 1
  for (int oc = 0; oc < 8; ++oc) {
    // stage w1 chunk (64 rows x 128 k, bf16 = 16KB)
    {
      const int row = tid >> 2, part = tid & 3;
      const uint4* g4 = (const uint4*)(w1p + (oc * 64 + row) * 128 + part * 32);
      uint4* d4 = (uint4*)(w1c + row * 136 + part * 32);
      #pragma unroll
      for (int i = 0; i < 4; ++i) d4[i] = g4[i];
    }
    // stage w2 chunk (128 c-rows x 64 o, bf16 = 16KB)
    {
      const int c = tid >> 1, hf = tid & 1;
      const uint4* g4 = (const uint4*)(w2p + c * 512 + oc * 64 + hf * 32);
      uint4* d4 = (uint4*)(w2c + c * 72 + hf * 32);
      #pragma unroll
      for (int i = 0; i < 4; ++i) d4[i] = g4[i];
    }
    __syncthreads();

    // h1 chunk GEMM: [64 tok] x [K=128] x [64 o], wave owns 16 o-cols
    f32x4 a1[4];
    #pragma unroll
    for (int t = 0; t < 4; ++t) a1[t] = zero4;
    #pragma unroll
    for (int ks = 0; ks < 4; ++ks) {
      const bf16x8 bfr = *(const bf16x8*)(w1c + (wave * 16 + l15) * 136 + ks * 32 + lg * 8);
      #pragma unroll
      for (int ti = 0; ti < 4; ++ti) {
        const bf16x8 afr = *(const bf16x8*)(xn + (ti * 16 + l15) * 136 + ks * 32 + lg * 8);
        a1[ti] = __builtin_amdgcn_mfma_f32_16x16x32_bf16(afr, bfr, a1[ti], 0, 0, 0);
      }
    }
    const int ol = wave * 16 + l15;
    const float b1v = b1[oc * 64 + ol];
    #pragma unroll
    for (int ti = 0; ti < 4; ++ti) {
      #pragma unroll
      for (int r = 0; r < 4; ++r) {
        const int tok = ti * 16 + lg * 4 + r;
        const float u = a1[ti][r] + b1v;
        const float ge = 0.5f * u * (1.0f + erff(u * 0.70710678118654752f));
        h1c[tok * 72 + ol] = f2bf(ge);
      }
    }
    __syncthreads();

    // h2 accumulate: [64 tok] x [k=64 o] x [128 c], wave owns 32 c-cols
    #pragma unroll
    for (int ks = 0; ks < 2; ++ks) {
      bf16x8 afr[4], bfr[2];
      #pragma unroll
      for (int ti = 0; ti < 4; ++ti)
        afr[ti] = *(const bf16x8*)(h1c + (ti * 16 + l15) * 72 + ks * 32 + lg * 8);
      #pragma unroll
      for (int tj = 0; tj < 2; ++tj)
        bfr[tj] = *(const bf16x8*)(w2c + (wave * 32 + tj * 16 + l15) * 72 + ks * 32 + lg * 8);
      #pragma unroll
      for (int ti = 0; ti < 4; ++ti)
        #pragma unroll
        for (int tj = 0; tj < 2; ++tj)
          acc2[ti][tj] = __builtin_amdgcn_mfma_f32_16x16x32_bf16(afr[ti], bfr[tj], acc2[ti][tj], 0, 0, 0);
    }
    __syncthreads();
  }

  // ---- epilogue: out = x1 + 0.5*(h2 + b2) ----
  #pragma unroll
  for (int tj = 0; tj < 2; ++tj) {
    const int c = wave * 32 + tj * 16 + l15;
    const float b2v = b2[c];
    #pragma unroll
    for (int ti = 0; ti < 4; ++ti) {
      #pragma unroll
      for (int r = 0; r < 4; ++r) {
        const int tokg = base + ti * 16 + lg * 4 + r;
        out[tokg * 128 + c] += 0.5f * (acc2[ti][tj][r] + b2v);
      }
    }
  }
}

extern "C" void kernel_launch(void* const* d_in, const int* in_sizes, int n_in,
                              void* d_out, int out_size, void* d_ws, size_t ws_size,
                              hipStream_t stream) {
  const float* x      = (const float*)d_in[0];
  const float* qkv_w  = (const float*)d_in[1];
  const float* rpb    = (const float*)d_in[2];
  const float* proj_w = (const float*)d_in[3];
  const float* proj_b = (const float*)d_in[4];
  const float* n1g    = (const float*)d_in[5];
  const float* n1b    = (const float*)d_in[6];
  const float* n2g    = (const float*)d_in[7];
  const float* n2b    = (const float*)d_in[8];
  const float* w1     = (const float*)d_in[9];
  const float* b1     = (const float*)d_in[10];
  const float* w2     = (const float*)d_in[11];
  const float* b2     = (const float*)d_in[12];
  const float* amask  = (const float*)d_in[13];
  const int*   rel    = (const int*)d_in[14];
  float* out  = (float*)d_out;

  unsigned char* ws = (unsigned char*)d_ws;
  float* bias = (float*)(ws);               // 64KB
  u16* qkv_p  = (u16*)(ws + 65536);         // 96KB
  u16* proj_p = (u16*)(ws + 163840);        // 32KB
  u16* w1p    = (u16*)(ws + 196608);        // 128KB
  u16* w2p    = (u16*)(ws + 327680);        // 128KB

  bias_kernel<<<64, 256, 0, stream>>>(rpb, rel, bias);
  pack_kernel<<<768, 256, 0, stream>>>(qkv_w, proj_w, w1, w2, qkv_p, proj_p, w1p, w2p);
  attn_kernel<<<2048, 512, 0, stream>>>(x, qkv_p, proj_p, proj_b, n1g, n1b, amask, bias, out);
  mlp_kernel<<<2048, 256, 0, stream>>>(w1p, b1, w2p, b2, n2g, n2b, out);
}

// Round 4
// 210.593 us; speedup vs baseline: 2.6178x; 1.2010x over previous
//
#include <hip/hip_runtime.h>

typedef unsigned short u16;
typedef unsigned int u32;
typedef short bf16x8 __attribute__((ext_vector_type(8)));
typedef float f32x4 __attribute__((ext_vector_type(4)));

__device__ __forceinline__ u16 f2bf(float f) {
  union { float f; u32 i; } v; v.f = f;
  u32 x = v.i;
  x += 0x7fff + ((x >> 16) & 1);   // RNE
  return (u16)(x >> 16);
}
__device__ __forceinline__ u32 pack2(float a, float b) {
  return (u32)f2bf(a) | ((u32)f2bf(b) << 16);
}

// ws layout (bytes):
//   bias  f32 [0, 65536)
//   qkv_p bf16 [65536, 163840)    (384x128, q-rows pre-scaled)
//   proj_p bf16 [163840, 196608)  (128x128)
//   w1p   bf16 [196608, 327680)   (512x128)
//   w2p   bf16 [327680, 458752)   (128x512)

// ---------------- kernel 0: bias gather + weight pack (merged) ----------------
__global__ void prep_kernel(const float* __restrict__ rpb, const int* __restrict__ rel,
                            const float* __restrict__ qkv_w, const float* __restrict__ proj_w,
                            const float* __restrict__ w1, const float* __restrict__ w2,
                            float* __restrict__ bias, u16* __restrict__ qkv_p,
                            u16* __restrict__ proj_p, u16* __restrict__ w1p,
                            u16* __restrict__ w2p) {
  const int bid = blockIdx.x;
  if (bid < 64) {
    const int idx = bid * 256 + threadIdx.x;   // 16384 bias entries
    const int h = idx >> 12, rm = idx & 4095;
    bias[idx] = rpb[rel[rm] * 4 + h];
  } else {
    const int i4 = (bid - 64) * 256 + threadIdx.x;  // 49152 float4 groups
    const int e = i4 * 4;
    const float scale = 0.17677669529663687f;       // 32^-0.5
    float4 v; u16* dst;
    if (e < 49152) {
      v = *(const float4*)(qkv_w + e);
      if (e < 16384) { v.x *= scale; v.y *= scale; v.z *= scale; v.w *= scale; }
      dst = qkv_p + e;
    } else if (e < 65536) {
      v = *(const float4*)(proj_w + (e - 49152));
      dst = proj_p + (e - 49152);
    } else if (e < 131072) {
      v = *(const float4*)(w1 + (e - 65536));
      dst = w1p + (e - 65536);
    } else {
      v = *(const float4*)(w2 + (e - 131072));
      dst = w2p + (e - 131072);
    }
    *(uint2*)dst = make_uint2(pack2(v.x, v.y), pack2(v.z, v.w));
  }
}

// ---------------- kernel 1: LN1 + shifted-window attention + proj + residual ----------------
// 2048 blocks x 512 threads (8 waves: wave = (half, head)); 2 blocks/CU
__global__ __launch_bounds__(512, 4) void attn_kernel(
    const float* __restrict__ x, const u16* __restrict__ qkv_p,
    const u16* __restrict__ proj_p, const float* __restrict__ proj_b,
    const float* __restrict__ n1g, const float* __restrict__ n1b,
    const float* __restrict__ amask, const float* __restrict__ bias,
    float* __restrict__ out)
{
  __shared__ __align__(16) unsigned char lds[70656];
  __shared__ int srcIdx[64];
  u16* xw = (u16*)(lds);            // [64][136] bf16
  u16* qb = (u16*)(lds + 17408);    // [64][136]
  u16* kb = (u16*)(lds + 34816);    // [64][136]
  u16* vt = (u16*)(lds + 52224);    // [128][72] channel-major V
  // Pb: per-wave [32 rows][64 cols] bf16, row stride 128B, XOR-swizzled slots.
  // 8 slices x 4096B = 32768B, overlaps xw+qb (dead after pre-P barrier).
  unsigned char* Pb = lds;
  u16* Ob = kb;                     // [64][136]

  const int tid = threadIdx.x;
  const int wv = tid >> 6, lane = tid & 63;
  const int l15 = lane & 15, lg = lane >> 4;
  const int hw = wv & 3;            // head
  const int half = wv >> 2;         // token half

  const int wIdx = blockIdx.x;
  const int bb = wIdx >> 9, ww = wIdx & 511;
  const int w0 = ww >> 6, w1i = (ww >> 3) & 7, w2i = ww & 7;

  // ---- LN1 + roll-gather into xw (8 threads per token) ----
  {
    const int tok = tid >> 3;
    const int qt = tid & 7;
    const int s0 = tok >> 4, s1 = (tok >> 2) & 3, s2 = tok & 3;
    const int p0 = (w0 * 4 + s0 + 2) & 31;
    const int p1 = (w1i * 4 + s1 + 2) & 31;
    const int p2 = (w2i * 4 + s2 + 2) & 31;
    const int src = (bb << 15) + (p0 << 10) + (p1 << 5) + p2;
    if (qt == 0) srcIdx[tok] = src;
    float v[16]; float s = 0.f, sq = 0.f;
    const float4* p4 = (const float4*)(x + src * 128 + qt * 16);
    #pragma unroll
    for (int i = 0; i < 4; ++i) {
      float4 u = p4[i];
      v[i * 4 + 0] = u.x; v[i * 4 + 1] = u.y; v[i * 4 + 2] = u.z; v[i * 4 + 3] = u.w;
      s += u.x + u.y + u.z + u.w;
      sq += u.x * u.x + u.y * u.y + u.z * u.z + u.w * u.w;
    }
    s  += __shfl_xor(s, 1);  s  += __shfl_xor(s, 2);  s  += __shfl_xor(s, 4);
    sq += __shfl_xor(sq, 1); sq += __shfl_xor(sq, 2); sq += __shfl_xor(sq, 4);
    const float mean = s * 0.0078125f;
    const float var  = sq * 0.0078125f - mean * mean;
    const float rstd = rsqrtf(var + 1e-5f);
    u16* dst = xw + tok * 136 + qt * 16;
    #pragma unroll
    for (int i = 0; i < 16; i += 2) {
      const int c = qt * 16 + i;
      float y0 = (v[i]     - mean) * rstd * n1g[c]     + n1b[c];
      float y1 = (v[i + 1] - mean) * rstd * n1g[c + 1] + n1b[c + 1];
      *(u32*)(dst + i) = pack2(y0, y1);
    }
  }
  __syncthreads();

  const f32x4 zero4 = {0.f, 0.f, 0.f, 0.f};

  // hoist this wave's xw A-fragments (its token half): 8 x bf16x8
  bf16x8 xa[2][4];
  #pragma unroll
  for (int ti = 0; ti < 2; ++ti)
    #pragma unroll
    for (int ks = 0; ks < 4; ++ks)
      xa[ti][ks] = *(const bf16x8*)(xw + ((half * 2 + ti) * 16 + l15) * 136 + ks * 32 + lg * 8);

  // ---- QKV with direct-global weight fragments (no LDS staging, no barriers) ----
  // Q chunks (cc 0,1)
  #pragma unroll
  for (int cc = 0; cc < 2; ++cc) {
    const u16* wp = qkv_p + (cc * 64 + hw * 16 + l15) * 128;
    f32x4 acc[2] = {zero4, zero4};
    #pragma unroll
    for (int ks = 0; ks < 4; ++ks) {
      const bf16x8 bfr = *(const bf16x8*)(wp + ks * 32 + lg * 8);
      acc[0] = __builtin_amdgcn_mfma_f32_16x16x32_bf16(xa[0][ks], bfr, acc[0], 0, 0, 0);
      acc[1] = __builtin_amdgcn_mfma_f32_16x16x32_bf16(xa[1][ks], bfr, acc[1], 0, 0, 0);
    }
    const int o = cc * 64 + hw * 16 + l15;
    #pragma unroll
    for (int ti = 0; ti < 2; ++ti)
      #pragma unroll
      for (int r = 0; r < 4; ++r)
        qb[((half * 2 + ti) * 16 + lg * 4 + r) * 136 + o] = f2bf(acc[ti][r]);
  }
  // K chunks (cc 2,3)
  #pragma unroll
  for (int cc = 2; cc < 4; ++cc) {
    const u16* wp = qkv_p + (cc * 64 + hw * 16 + l15) * 128;
    f32x4 acc[2] = {zero4, zero4};
    #pragma unroll
    for (int ks = 0; ks < 4; ++ks) {
      const bf16x8 bfr = *(const bf16x8*)(wp + ks * 32 + lg * 8);
      acc[0] = __builtin_amdgcn_mfma_f32_16x16x32_bf16(xa[0][ks], bfr, acc[0], 0, 0, 0);
      acc[1] = __builtin_amdgcn_mfma_f32_16x16x32_bf16(xa[1][ks], bfr, acc[1], 0, 0, 0);
    }
    const int o = (cc - 2) * 64 + hw * 16 + l15;
    #pragma unroll
    for (int ti = 0; ti < 2; ++ti)
      #pragma unroll
      for (int r = 0; r < 4; ++r)
        kb[((half * 2 + ti) * 16 + lg * 4 + r) * 136 + o] = f2bf(acc[ti][r]);
  }
  // V chunks (cc 4,5) -> channel-major vt
  #pragma unroll
  for (int cc = 4; cc < 6; ++cc) {
    const u16* wp = qkv_p + (cc * 64 + hw * 16 + l15) * 128;
    f32x4 acc[2] = {zero4, zero4};
    #pragma unroll
    for (int ks = 0; ks < 4; ++ks) {
      const bf16x8 bfr = *(const bf16x8*)(wp + ks * 32 + lg * 8);
      acc[0] = __builtin_amdgcn_mfma_f32_16x16x32_bf16(xa[0][ks], bfr, acc[0], 0, 0, 0);
      acc[1] = __builtin_amdgcn_mfma_f32_16x16x32_bf16(xa[1][ks], bfr, acc[1], 0, 0, 0);
    }
    const int cvch = (cc - 4) * 64 + hw * 16 + l15;   // v channel 0..127
    #pragma unroll
    for (int ti = 0; ti < 2; ++ti)
      #pragma unroll
      for (int r = 0; r < 4; ++r)
        vt[cvch * 72 + (half * 2 + ti) * 16 + lg * 4 + r] = f2bf(acc[ti][r]);
  }
  __syncthreads();

  // ---- QK^T (K=32 = head dim) ----
  f32x4 s[2][4];
  {
    bf16x8 qa[2];
    #pragma unroll
    for (int ti = 0; ti < 2; ++ti)
      qa[ti] = *(const bf16x8*)(qb + ((half * 2 + ti) * 16 + l15) * 136 + hw * 32 + lg * 8);
    #pragma unroll
    for (int tj = 0; tj < 4; ++tj) {
      const bf16x8 kf = *(const bf16x8*)(kb + (tj * 16 + l15) * 136 + hw * 32 + lg * 8);
      s[0][tj] = __builtin_amdgcn_mfma_f32_16x16x32_bf16(qa[0], kf, zero4, 0, 0, 0);
      s[1][tj] = __builtin_amdgcn_mfma_f32_16x16x32_bf16(qa[1], kf, zero4, 0, 0, 0);
    }
  }
  // bias + shift mask
  #pragma unroll
  for (int ti = 0; ti < 2; ++ti) {
    #pragma unroll
    for (int r = 0; r < 4; ++r) {
      const int row = (half * 2 + ti) * 16 + lg * 4 + r;
      const float* bp = bias + hw * 4096 + row * 64;
      const float* mp = amask + ww * 4096 + row * 64;
      #pragma unroll
      for (int tj = 0; tj < 4; ++tj) {
        const int col = tj * 16 + l15;
        s[ti][tj][r] += bp[col] + mp[col];
      }
    }
  }
  __syncthreads();   // all xw/qb LDS reads done before Pb overwrites

  // ---- softmax + P write (wave-private swizzled slice) ----
  unsigned char* ps = Pb + wv * 4096;   // [32][128B]
  float rcp[2][4];
  #pragma unroll
  for (int ti = 0; ti < 2; ++ti) {
    #pragma unroll
    for (int r = 0; r < 4; ++r) {
      float mx = fmaxf(fmaxf(s[ti][0][r], s[ti][1][r]), fmaxf(s[ti][2][r], s[ti][3][r]));
      mx = fmaxf(mx, __shfl_xor(mx, 1));
      mx = fmaxf(mx, __shfl_xor(mx, 2));
      mx = fmaxf(mx, __shfl_xor(mx, 4));
      mx = fmaxf(mx, __shfl_xor(mx, 8));
      float sum = 0.f;
      #pragma unroll
      for (int tj = 0; tj < 4; ++tj) {
        float e = __expf(s[ti][tj][r] - mx);
        s[ti][tj][r] = e; sum += e;
      }
      sum += __shfl_xor(sum, 1);
      sum += __shfl_xor(sum, 2);
      sum += __shfl_xor(sum, 4);
      sum += __shfl_xor(sum, 8);
      rcp[ti][r] = 1.0f / sum;
      const int row = ti * 16 + lg * 4 + r;          // slice-local row
      const int swz = (row & 7) << 4;
      #pragma unroll
      for (int tj = 0; tj < 4; ++tj) {
        const int byteoff = (row * 128 + (tj * 16 + l15) * 2) ^ swz;
        *(u16*)(ps + byteoff) = f2bf(s[ti][tj][r]);  // unnormalized
      }
    }
  }
  // no barrier: slice is wave-private

  // ---- PV ----
  {
    f32x4 oacc[2][2] = {{zero4, zero4}, {zero4, zero4}};
    #pragma unroll
    for (int ks = 0; ks < 2; ++ks) {
      bf16x8 pa[2], vb[2];
      #pragma unroll
      for (int ti = 0; ti < 2; ++ti) {
        const int row = ti * 16 + l15;
        const int slot = ((ks * 4 + lg) ^ (row & 7)) << 4;
        pa[ti] = *(const bf16x8*)(ps + row * 128 + slot);
      }
      #pragma unroll
      for (int tj = 0; tj < 2; ++tj)
        vb[tj] = *(const bf16x8*)(vt + (hw * 32 + tj * 16 + l15) * 72 + ks * 32 + lg * 8);
      #pragma unroll
      for (int ti = 0; ti < 2; ++ti)
        #pragma unroll
        for (int tj = 0; tj < 2; ++tj)
          oacc[ti][tj] = __builtin_amdgcn_mfma_f32_16x16x32_bf16(pa[ti], vb[tj], oacc[ti][tj], 0, 0, 0);
    }
    #pragma unroll
    for (int ti = 0; ti < 2; ++ti)
      #pragma unroll
      for (int tj = 0; tj < 2; ++tj)
        #pragma unroll
        for (int r = 0; r < 4; ++r) {
          const int tok = (half * 2 + ti) * 16 + lg * 4 + r;
          Ob[tok * 136 + hw * 32 + tj * 16 + l15] = f2bf(oacc[ti][tj][r] * rcp[ti][r]);
        }
  }
  __syncthreads();   // O visible to all waves

  // ---- proj (direct-global weights) + residual epilogue ----
  #pragma unroll
  for (int cc = 0; cc < 2; ++cc) {
    const u16* wp = proj_p + (cc * 64 + hw * 16 + l15) * 128;
    f32x4 acc[2] = {zero4, zero4};
    #pragma unroll
    for (int ks = 0; ks < 4; ++ks) {
      const bf16x8 bfr = *(const bf16x8*)(wp + ks * 32 + lg * 8);
      #pragma unroll
      for (int ti = 0; ti < 2; ++ti) {
        const bf16x8 afr = *(const bf16x8*)(Ob + ((half * 2 + ti) * 16 + l15) * 136 + ks * 32 + lg * 8);
        acc[ti] = __builtin_amdgcn_mfma_f32_16x16x32_bf16(afr, bfr, acc[ti], 0, 0, 0);
      }
    }
    const int c = cc * 64 + hw * 16 + l15;
    const float pbv = proj_b[c];
    #pragma unroll
    for (int ti = 0; ti < 2; ++ti) {
      #pragma unroll
      for (int r = 0; r < 4; ++r) {
        const int tok = (half * 2 + ti) * 16 + lg * 4 + r;
        const int src = srcIdx[tok];
        out[src * 128 + c] = x[src * 128 + c] + 0.5f * (acc[ti][r] + pbv);
      }
    }
  }
}

// ---------------- kernel 2: LN2 + MLP + residual (35.8KB LDS, 4 blocks/CU) ----------------
__global__ __launch_bounds__(256, 4) void mlp_kernel(
    const u16* __restrict__ w1p, const float* __restrict__ b1,
    const u16* __restrict__ w2p, const float* __restrict__ b2,
    const float* __restrict__ n2g, const float* __restrict__ n2b,
    float* __restrict__ out)
{
  __shared__ __align__(16) unsigned char lds[35840];
  u16* xn  = (u16*)(lds);           // [64][136] bf16
  u16* h1c0 = (u16*)(lds + 17408);  // [64][72] gelu chunk, buffer 0
  u16* h1c1 = (u16*)(lds + 26624);  // [64][72] buffer 1

  const int tid = threadIdx.x;
  const int wave = tid >> 6, lane = tid & 63;
  const int l15 = lane & 15, lg = lane >> 4;
  const int base = blockIdx.x * 64;
  const f32x4 zero4 = {0.f, 0.f, 0.f, 0.f};

  // ---- LN2 over x1 (read from out) ----
  {
    const int tl = tid >> 2;
    const int qt = tid & 3;
    const int tokg = base + tl;
    float v[32]; float s = 0.f, sq = 0.f;
    const float4* p4 = (const float4*)(out + tokg * 128 + qt * 32);
    #pragma unroll
    for (int i = 0; i < 8; ++i) {
      float4 u = p4[i];
      v[i * 4 + 0] = u.x; v[i * 4 + 1] = u.y; v[i * 4 + 2] = u.z; v[i * 4 + 3] = u.w;
      s += u.x + u.y + u.z + u.w;
      sq += u.x * u.x + u.y * u.y + u.z * u.z + u.w * u.w;
    }
    s  += __shfl_xor(s, 1);  s  += __shfl_xor(s, 2);
    sq += __shfl_xor(sq, 1); sq += __shfl_xor(sq, 2);
    const float mean = s * 0.0078125f;
    const float var  = sq * 0.0078125f - mean * mean;
    const float rstd = rsqrtf(var + 1e-5f);
    u16* dst = xn + tl * 136 + qt * 32;
    #pragma unroll
    for (int i = 0; i < 32; i += 2) {
      const int c = qt * 32 + i;
      float y0 = (v[i]     - mean) * rstd * n2g[c]     + n2b[c];
      float y1 = (v[i + 1] - mean) * rstd * n2g[c + 1] + n2b[c + 1];
      *(u32*)(dst + i) = pack2(y0, y1);
    }
  }
  __syncthreads();

  f32x4 acc2[4][2];
  #pragma unroll
  for (int ti = 0; ti < 4; ++ti) { acc2[ti][0] = zero4; acc2[ti][1] = zero4; }

  #pragma unroll 1
  for (int oc = 0; oc < 8; ++oc) {
    u16* h1c = (oc & 1) ? h1c1 : h1c0;
    // h1 chunk GEMM: direct-global w1 fragments
    f32x4 a1[4];
    #pragma unroll
    for (int t = 0; t < 4; ++t) a1[t] = zero4;
    const u16* wp1 = w1p + (oc * 64 + wave * 16 + l15) * 128;
    #pragma unroll
    for (int ks = 0; ks < 4; ++ks) {
      const bf16x8 bfr = *(const bf16x8*)(wp1 + ks * 32 + lg * 8);
      #pragma unroll
      for (int ti = 0; ti < 4; ++ti) {
        const bf16x8 afr = *(const bf16x8*)(xn + (ti * 16 + l15) * 136 + ks * 32 + lg * 8);
        a1[ti] = __builtin_amdgcn_mfma_f32_16x16x32_bf16(afr, bfr, a1[ti], 0, 0, 0);
      }
    }
    const int ol = wave * 16 + l15;
    const float b1v = b1[oc * 64 + ol];
    #pragma unroll
    for (int ti = 0; ti < 4; ++ti) {
      #pragma unroll
      for (int r = 0; r < 4; ++r) {
        const int tok = ti * 16 + lg * 4 + r;
        const float u = a1[ti][r] + b1v;
        const float ge = 0.5f * u * (1.0f + erff(u * 0.70710678118654752f));
        h1c[tok * 72 + ol] = f2bf(ge);
      }
    }
    __syncthreads();

    // h2 accumulate: direct-global w2 fragments
    #pragma unroll
    for (int ks = 0; ks < 2; ++ks) {
      bf16x8 afr[4], bfr[2];
      #pragma unroll
      for (int ti = 0; ti < 4; ++ti)
        afr[ti] = *(const bf16x8*)(h1c + (ti * 16 + l15) * 72 + ks * 32 + lg * 8);
      #pragma unroll
      for (int tj = 0; tj < 2; ++tj)
        bfr[tj] = *(const bf16x8*)(w2p + (wave * 32 + tj * 16 + l15) * 512 + oc * 64 + ks * 32 + lg * 8);
      #pragma unroll
      for (int ti = 0; ti < 4; ++ti)
        #pragma unroll
        for (int tj = 0; tj < 2; ++tj)
          acc2[ti][tj] = __builtin_amdgcn_mfma_f32_16x16x32_bf16(afr[ti], bfr[tj], acc2[ti][tj], 0, 0, 0);
    }
  }

  // ---- epilogue: out = x1 + 0.5*(h2 + b2) ----
  #pragma unroll
  for (int tj = 0; tj < 2; ++tj) {
    const int c = wave * 32 + tj * 16 + l15;
    const float b2v = b2[c];
    #pragma unroll
    for (int ti = 0; ti < 4; ++ti) {
      #pragma unroll
      for (int r = 0; r < 4; ++r) {
        const int tokg = base + ti * 16 + lg * 4 + r;
        out[tokg * 128 + c] += 0.5f * (acc2[ti][tj][r] + b2v);
      }
    }
  }
}

extern "C" void kernel_launch(void* const* d_in, const int* in_sizes, int n_in,
                              void* d_out, int out_size, void* d_ws, size_t ws_size,
                              hipStream_t stream) {
  const float* x      = (const float*)d_in[0];
  const float* qkv_w  = (const float*)d_in[1];
  const float* rpb    = (const float*)d_in[2];
  const float* proj_w = (const float*)d_in[3];
  const float* proj_b = (const float*)d_in[4];
  const float* n1g    = (const float*)d_in[5];
  const float* n1b    = (const float*)d_in[6];
  const float* n2g    = (const float*)d_in[7];
  const float* n2b    = (const float*)d_in[8];
  const float* w1     = (const float*)d_in[9];
  const float* b1     = (const float*)d_in[10];
  const float* w2     = (const float*)d_in[11];
  const float* b2     = (const float*)d_in[12];
  const float* amask  = (const float*)d_in[13];
  const int*   rel    = (const int*)d_in[14];
  float* out  = (float*)d_out;

  unsigned char* ws = (unsigned char*)d_ws;
  float* bias = (float*)(ws);               // 64KB
  u16* qkv_p  = (u16*)(ws + 65536);         // 96KB
  u16* proj_p = (u16*)(ws + 163840);        // 32KB
  u16* w1p    = (u16*)(ws + 196608);        // 128KB
  u16* w2p    = (u16*)(ws + 327680);        // 128KB

  prep_kernel<<<256, 256, 0, stream>>>(rpb, rel, qkv_w, proj_w, w1, w2,
                                       bias, qkv_p, proj_p, w1p, w2p);
  attn_kernel<<<2048, 512, 0, stream>>>(x, qkv_p, proj_p, proj_b, n1g, n1b, amask, bias, out);
  mlp_kernel<<<2048, 256, 0, stream>>>(w1p, b1, w2p, b2, n2g, n2b, out);
}

// Round 5
// 161.400 us; speedup vs baseline: 3.4157x; 1.3048x over previous
//
#include <hip/hip_runtime.h>

typedef unsigned short u16;
typedef unsigned int u32;
typedef short bf16x8 __attribute__((ext_vector_type(8)));
typedef float f32x4 __attribute__((ext_vector_type(4)));

__device__ __forceinline__ u16 f2bf(float f) {
  union { float f; u32 i; } v; v.f = f;
  u32 x = v.i;
  x += 0x7fff + ((x >> 16) & 1);   // RNE
  return (u16)(x >> 16);
}
__device__ __forceinline__ u32 pack2(float a, float b) {
  return (u32)f2bf(a) | ((u32)f2bf(b) << 16);
}

// ws layout (bytes):
//   bias  f32 [0, 65536)
//   qkv_f bf16 [65536, 163840)    (384x128 in MFMA-fragment tile order, q pre-scaled)
//   proj_f bf16 [163840, 196608)  (128x128 fragment order)
//   w1f   bf16 [196608, 327680)   (512x128 fragment order)
//   w2f   bf16 [327680, 458752)   (128x512 fragment order)
// Fragment order: tile(16 rows x 32 k) -> [tile][lane=((k>>3)&3)*16+(row&15)][k&7]

// ---------------- kernel 0: bias gather + fragment-order weight pack ----------------
__global__ void prep_kernel(const float* __restrict__ rpb, const int* __restrict__ rel,
                            const float* __restrict__ qkv_w, const float* __restrict__ proj_w,
                            const float* __restrict__ w1, const float* __restrict__ w2,
                            float* __restrict__ bias, u16* __restrict__ qkv_f,
                            u16* __restrict__ proj_f, u16* __restrict__ w1f,
                            u16* __restrict__ w2f) {
  const int bid = blockIdx.x;
  if (bid < 64) {
    const int idx = bid * 256 + threadIdx.x;   // 16384 bias entries
    const int h = idx >> 12, rm = idx & 4095;
    bias[idx] = rpb[rel[rm] * 4 + h];
    return;
  }
  const int i4 = (bid - 64) * 256 + threadIdx.x;  // 49152 float4 groups
  const int e = i4 * 4;
  const float scale = 0.17677669529663687f;       // 32^-0.5
  float4 v; u16* dst;
  if (e < 49152) {            // qkv 384x128
    v = *(const float4*)(qkv_w + e);
    if (e < 16384) { v.x *= scale; v.y *= scale; v.z *= scale; v.w *= scale; }
    const int row = e >> 7, col = e & 127;
    const int tile = (row >> 4) * 4 + (col >> 5);
    const int lane = ((col >> 3) & 3) * 16 + (row & 15);
    dst = qkv_f + tile * 512 + lane * 8 + (col & 7);
  } else if (e < 65536) {     // proj 128x128
    const int le = e - 49152;
    v = *(const float4*)(proj_w + le);
    const int row = le >> 7, col = le & 127;
    const int tile = (row >> 4) * 4 + (col >> 5);
    const int lane = ((col >> 3) & 3) * 16 + (row & 15);
    dst = proj_f + tile * 512 + lane * 8 + (col & 7);
  } else if (e < 131072) {    // w1 512x128
    const int le = e - 65536;
    v = *(const float4*)(w1 + le);
    const int row = le >> 7, col = le & 127;
    const int tile = (row >> 4) * 4 + (col >> 5);
    const int lane = ((col >> 3) & 3) * 16 + (row & 15);
    dst = w1f + tile * 512 + lane * 8 + (col & 7);
  } else {                    // w2 128x512
    const int le = e - 131072;
    v = *(const float4*)(w2 + le);
    const int row = le >> 9, col = le & 511;
    const int tile = (row >> 4) * 16 + (col >> 5);
    const int lane = ((col >> 3) & 3) * 16 + (row & 15);
    dst = w2f + tile * 512 + lane * 8 + (col & 7);
  }
  *(uint2*)dst = make_uint2(pack2(v.x, v.y), pack2(v.z, v.w));
}

// ---------------- kernel 1: LN1 + shifted-window attention + proj + residual ----------------
// 2048 blocks x 512 threads (8 waves: wave = (half, head)); 2 blocks/CU
__global__ __launch_bounds__(512, 4) void attn_kernel(
    const float* __restrict__ x, const u16* __restrict__ qkv_f,
    const u16* __restrict__ proj_f, const float* __restrict__ proj_b,
    const float* __restrict__ n1g, const float* __restrict__ n1b,
    const float* __restrict__ amask, const float* __restrict__ bias,
    float* __restrict__ out)
{
  __shared__ __align__(16) unsigned char lds[70656];
  __shared__ int srcIdx[64];
  u16* xw = (u16*)(lds);            // [64][136] bf16
  u16* qb = (u16*)(lds + 17408);    // [64][136]
  u16* kb = (u16*)(lds + 34816);    // [64][136]
  u16* vt = (u16*)(lds + 52224);    // [128][72] channel-major V
  unsigned char* Pb = lds;          // 8 x [32][128B] swizzled, overlaps xw+qb (dead)
  u16* Ob = kb;                     // [64][136]

  const int tid = threadIdx.x;
  const int wv = tid >> 6, lane = tid & 63;
  const int l15 = lane & 15, lg = lane >> 4;
  const int hw = wv & 3;            // head
  const int half = wv >> 2;         // token half

  const int wIdx = blockIdx.x;
  const int bb = wIdx >> 9, ww = wIdx & 511;
  const int w0 = ww >> 6, w1i = (ww >> 3) & 7, w2i = ww & 7;

  // ---- LN1 + roll-gather into xw (8 threads per token) ----
  {
    const int tok = tid >> 3;
    const int qt = tid & 7;
    const int s0 = tok >> 4, s1 = (tok >> 2) & 3, s2 = tok & 3;
    const int p0 = (w0 * 4 + s0 + 2) & 31;
    const int p1 = (w1i * 4 + s1 + 2) & 31;
    const int p2 = (w2i * 4 + s2 + 2) & 31;
    const int src = (bb << 15) + (p0 << 10) + (p1 << 5) + p2;
    if (qt == 0) srcIdx[tok] = src;
    float v[16]; float s = 0.f, sq = 0.f;
    const float4* p4 = (const float4*)(x + src * 128 + qt * 16);
    #pragma unroll
    for (int i = 0; i < 4; ++i) {
      float4 u = p4[i];
      v[i * 4 + 0] = u.x; v[i * 4 + 1] = u.y; v[i * 4 + 2] = u.z; v[i * 4 + 3] = u.w;
      s += u.x + u.y + u.z + u.w;
      sq += u.x * u.x + u.y * u.y + u.z * u.z + u.w * u.w;
    }
    s  += __shfl_xor(s, 1);  s  += __shfl_xor(s, 2);  s  += __shfl_xor(s, 4);
    sq += __shfl_xor(sq, 1); sq += __shfl_xor(sq, 2); sq += __shfl_xor(sq, 4);
    const float mean = s * 0.0078125f;
    const float var  = sq * 0.0078125f - mean * mean;
    const float rstd = rsqrtf(var + 1e-5f);
    u16* dst = xw + tok * 136 + qt * 16;
    #pragma unroll
    for (int i = 0; i < 16; i += 2) {
      const int c = qt * 16 + i;
      float y0 = (v[i]     - mean) * rstd * n1g[c]     + n1b[c];
      float y1 = (v[i + 1] - mean) * rstd * n1g[c + 1] + n1b[c + 1];
      *(u32*)(dst + i) = pack2(y0, y1);
    }
  }
  __syncthreads();

  const f32x4 zero4 = {0.f, 0.f, 0.f, 0.f};

  // hoist this wave's xw A-fragments: 8 x bf16x8
  bf16x8 xa[2][4];
  #pragma unroll
  for (int ti = 0; ti < 2; ++ti)
    #pragma unroll
    for (int ks = 0; ks < 4; ++ks)
      xa[ti][ks] = *(const bf16x8*)(xw + ((half * 2 + ti) * 16 + l15) * 136 + ks * 32 + lg * 8);

  // ---- QKV: fragment-order weights, fully coalesced loads ----
  // Q chunks (cc 0,1)
  #pragma unroll
  for (int cc = 0; cc < 2; ++cc) {
    const u16* wp = qkv_f + (cc * 4 + hw) * 4 * 512 + lane * 8;
    f32x4 acc[2] = {zero4, zero4};
    #pragma unroll
    for (int ks = 0; ks < 4; ++ks) {
      const bf16x8 bfr = *(const bf16x8*)(wp + ks * 512);
      acc[0] = __builtin_amdgcn_mfma_f32_16x16x32_bf16(xa[0][ks], bfr, acc[0], 0, 0, 0);
      acc[1] = __builtin_amdgcn_mfma_f32_16x16x32_bf16(xa[1][ks], bfr, acc[1], 0, 0, 0);
    }
    const int o = cc * 64 + hw * 16 + l15;
    #pragma unroll
    for (int ti = 0; ti < 2; ++ti)
      #pragma unroll
      for (int r = 0; r < 4; ++r)
        qb[((half * 2 + ti) * 16 + lg * 4 + r) * 136 + o] = f2bf(acc[ti][r]);
  }
  // K chunks (cc 2,3)
  #pragma unroll
  for (int cc = 2; cc < 4; ++cc) {
    const u16* wp = qkv_f + (cc * 4 + hw) * 4 * 512 + lane * 8;
    f32x4 acc[2] = {zero4, zero4};
    #pragma unroll
    for (int ks = 0; ks < 4; ++ks) {
      const bf16x8 bfr = *(const bf16x8*)(wp + ks * 512);
      acc[0] = __builtin_amdgcn_mfma_f32_16x16x32_bf16(xa[0][ks], bfr, acc[0], 0, 0, 0);
      acc[1] = __builtin_amdgcn_mfma_f32_16x16x32_bf16(xa[1][ks], bfr, acc[1], 0, 0, 0);
    }
    const int o = (cc - 2) * 64 + hw * 16 + l15;
    #pragma unroll
    for (int ti = 0; ti < 2; ++ti)
      #pragma unroll
      for (int r = 0; r < 4; ++r)
        kb[((half * 2 + ti) * 16 + lg * 4 + r) * 136 + o] = f2bf(acc[ti][r]);
  }
  // V chunks (cc 4,5) -> channel-major vt, packed 8B writes
  #pragma unroll
  for (int cc = 4; cc < 6; ++cc) {
    const u16* wp = qkv_f + (cc * 4 + hw) * 4 * 512 + lane * 8;
    f32x4 acc[2] = {zero4, zero4};
    #pragma unroll
    for (int ks = 0; ks < 4; ++ks) {
      const bf16x8 bfr = *(const bf16x8*)(wp + ks * 512);
      acc[0] = __builtin_amdgcn_mfma_f32_16x16x32_bf16(xa[0][ks], bfr, acc[0], 0, 0, 0);
      acc[1] = __builtin_amdgcn_mfma_f32_16x16x32_bf16(xa[1][ks], bfr, acc[1], 0, 0, 0);
    }
    const int cvch = (cc - 4) * 64 + hw * 16 + l15;   // v channel 0..127
    #pragma unroll
    for (int ti = 0; ti < 2; ++ti) {
      uint2 pk = make_uint2(pack2(acc[ti][0], acc[ti][1]), pack2(acc[ti][2], acc[ti][3]));
      *(uint2*)(vt + cvch * 72 + (half * 2 + ti) * 16 + lg * 4) = pk;
    }
  }
  __syncthreads();

  // ---- QK^T (K=32 = head dim) ----
  f32x4 s[2][4];
  {
    bf16x8 qa[2];
    #pragma unroll
    for (int ti = 0; ti < 2; ++ti)
      qa[ti] = *(const bf16x8*)(qb + ((half * 2 + ti) * 16 + l15) * 136 + hw * 32 + lg * 8);
    #pragma unroll
    for (int tj = 0; tj < 4; ++tj) {
      const bf16x8 kf = *(const bf16x8*)(kb + (tj * 16 + l15) * 136 + hw * 32 + lg * 8);
      s[0][tj] = __builtin_amdgcn_mfma_f32_16x16x32_bf16(qa[0], kf, zero4, 0, 0, 0);
      s[1][tj] = __builtin_amdgcn_mfma_f32_16x16x32_bf16(qa[1], kf, zero4, 0, 0, 0);
    }
  }
  // bias + shift mask
  #pragma unroll
  for (int ti = 0; ti < 2; ++ti) {
    #pragma unroll
    for (int r = 0; r < 4; ++r) {
      const int row = (half * 2 + ti) * 16 + lg * 4 + r;
      const float* bp = bias + hw * 4096 + row * 64;
      const float* mp = amask + ww * 4096 + row * 64;
      #pragma unroll
      for (int tj = 0; tj < 4; ++tj) {
        const int col = tj * 16 + l15;
        s[ti][tj][r] += bp[col] + mp[col];
      }
    }
  }
  __syncthreads();   // all xw/qb LDS reads done before Pb overwrites

  // ---- softmax + P write (wave-private swizzled slice) ----
  unsigned char* ps = Pb + wv * 4096;   // [32][128B]
  float rcp[2][4];
  #pragma unroll
  for (int ti = 0; ti < 2; ++ti) {
    #pragma unroll
    for (int r = 0; r < 4; ++r) {
      float mx = fmaxf(fmaxf(s[ti][0][r], s[ti][1][r]), fmaxf(s[ti][2][r], s[ti][3][r]));
      mx = fmaxf(mx, __shfl_xor(mx, 1));
      mx = fmaxf(mx, __shfl_xor(mx, 2));
      mx = fmaxf(mx, __shfl_xor(mx, 4));
      mx = fmaxf(mx, __shfl_xor(mx, 8));
      float sum = 0.f;
      #pragma unroll
      for (int tj = 0; tj < 4; ++tj) {
        float e = __expf(s[ti][tj][r] - mx);
        s[ti][tj][r] = e; sum += e;
      }
      sum += __shfl_xor(sum, 1);
      sum += __shfl_xor(sum, 2);
      sum += __shfl_xor(sum, 4);
      sum += __shfl_xor(sum, 8);
      rcp[ti][r] = 1.0f / sum;
      const int row = ti * 16 + lg * 4 + r;          // slice-local row
      const int swz = (row & 7) << 4;
      #pragma unroll
      for (int tj = 0; tj < 4; ++tj) {
        const int byteoff = (row * 128 + (tj * 16 + l15) * 2) ^ swz;
        *(u16*)(ps + byteoff) = f2bf(s[ti][tj][r]);  // unnormalized
      }
    }
  }
  // no barrier: slice is wave-private

  // ---- PV ----
  {
    f32x4 oacc[2][2] = {{zero4, zero4}, {zero4, zero4}};
    #pragma unroll
    for (int ks = 0; ks < 2; ++ks) {
      bf16x8 pa[2], vb[2];
      #pragma unroll
      for (int ti = 0; ti < 2; ++ti) {
        const int row = ti * 16 + l15;
        const int slot = ((ks * 4 + lg) ^ (row & 7)) << 4;
        pa[ti] = *(const bf16x8*)(ps + row * 128 + slot);
      }
      #pragma unroll
      for (int tj = 0; tj < 2; ++tj)
        vb[tj] = *(const bf16x8*)(vt + (hw * 32 + tj * 16 + l15) * 72 + ks * 32 + lg * 8);
      #pragma unroll
      for (int ti = 0; ti < 2; ++ti)
        #pragma unroll
        for (int tj = 0; tj < 2; ++tj)
          oacc[ti][tj] = __builtin_amdgcn_mfma_f32_16x16x32_bf16(pa[ti], vb[tj], oacc[ti][tj], 0, 0, 0);
    }
    #pragma unroll
    for (int ti = 0; ti < 2; ++ti)
      #pragma unroll
      for (int tj = 0; tj < 2; ++tj)
        #pragma unroll
        for (int r = 0; r < 4; ++r) {
          const int tok = (half * 2 + ti) * 16 + lg * 4 + r;
          Ob[tok * 136 + hw * 32 + tj * 16 + l15] = f2bf(oacc[ti][tj][r] * rcp[ti][r]);
        }
  }
  __syncthreads();   // O visible to all waves

  // ---- proj (fragment-order weights, hoisted A-frags) + residual epilogue ----
  bf16x8 oafr[2][4];
  #pragma unroll
  for (int ti = 0; ti < 2; ++ti)
    #pragma unroll
    for (int ks = 0; ks < 4; ++ks)
      oafr[ti][ks] = *(const bf16x8*)(Ob + ((half * 2 + ti) * 16 + l15) * 136 + ks * 32 + lg * 8);
  #pragma unroll
  for (int cc = 0; cc < 2; ++cc) {
    const u16* wp = proj_f + (cc * 4 + hw) * 4 * 512 + lane * 8;
    f32x4 acc[2] = {zero4, zero4};
    #pragma unroll
    for (int ks = 0; ks < 4; ++ks) {
      const bf16x8 bfr = *(const bf16x8*)(wp + ks * 512);
      acc[0] = __builtin_amdgcn_mfma_f32_16x16x32_bf16(oafr[0][ks], bfr, acc[0], 0, 0, 0);
      acc[1] = __builtin_amdgcn_mfma_f32_16x16x32_bf16(oafr[1][ks], bfr, acc[1], 0, 0, 0);
    }
    const int c = cc * 64 + hw * 16 + l15;
    const float pbv = proj_b[c];
    #pragma unroll
    for (int ti = 0; ti < 2; ++ti) {
      #pragma unroll
      for (int r = 0; r < 4; ++r) {
        const int tok = (half * 2 + ti) * 16 + lg * 4 + r;
        const int src = srcIdx[tok];
        out[src * 128 + c] = x[src * 128 + c] + 0.5f * (acc[ti][r] + pbv);
      }
    }
  }
}

// ---------------- kernel 2: LN2 + MLP + residual (35.8KB LDS, 4 blocks/CU) ----------------
__global__ __launch_bounds__(256, 4) void mlp_kernel(
    const u16* __restrict__ w1f, const float* __restrict__ b1,
    const u16* __restrict__ w2f, const float* __restrict__ b2,
    const float* __restrict__ n2g, const float* __restrict__ n2b,
    float* __restrict__ out)
{
  __shared__ __align__(16) unsigned char lds[35840];
  u16* xn  = (u16*)(lds);           // [64][136] bf16
  u16* h1c0 = (u16*)(lds + 17408);  // [64][72] gelu chunk, buffer 0
  u16* h1c1 = (u16*)(lds + 26624);  // [64][72] buffer 1

  const int tid = threadIdx.x;
  const int wave = tid >> 6, lane = tid & 63;
  const int l15 = lane & 15, lg = lane >> 4;
  const int base = blockIdx.x * 64;
  const f32x4 zero4 = {0.f, 0.f, 0.f, 0.f};

  // ---- LN2 over x1 (read from out) ----
  {
    const int tl = tid >> 2;
    const int qt = tid & 3;
    const int tokg = base + tl;
    float v[32]; float s = 0.f, sq = 0.f;
    const float4* p4 = (const float4*)(out + tokg * 128 + qt * 32);
    #pragma unroll
    for (int i = 0; i < 8; ++i) {
      float4 u = p4[i];
      v[i * 4 + 0] = u.x; v[i * 4 + 1] = u.y; v[i * 4 + 2] = u.z; v[i * 4 + 3] = u.w;
      s += u.x + u.y + u.z + u.w;
      sq += u.x * u.x + u.y * u.y + u.z * u.z + u.w * u.w;
    }
    s  += __shfl_xor(s, 1);  s  += __shfl_xor(s, 2);
    sq += __shfl_xor(sq, 1); sq += __shfl_xor(sq, 2);
    const float mean = s * 0.0078125f;
    const float var  = sq * 0.0078125f - mean * mean;
    const float rstd = rsqrtf(var + 1e-5f);
    u16* dst = xn + tl * 136 + qt * 32;
    #pragma unroll
    for (int i = 0; i < 32; i += 2) {
      const int c = qt * 32 + i;
      float y0 = (v[i]     - mean) * rstd * n2g[c]     + n2b[c];
      float y1 = (v[i + 1] - mean) * rstd * n2g[c + 1] + n2b[c + 1];
      *(u32*)(dst + i) = pack2(y0, y1);
    }
  }
  __syncthreads();

  f32x4 acc2[4][2];
  #pragma unroll
  for (int ti = 0; ti < 4; ++ti) { acc2[ti][0] = zero4; acc2[ti][1] = zero4; }

  #pragma unroll 1
  for (int oc = 0; oc < 8; ++oc) {
    u16* h1c = (oc & 1) ? h1c1 : h1c0;
    // h1 chunk GEMM: fragment-order w1, coalesced
    f32x4 a1[4];
    #pragma unroll
    for (int t = 0; t < 4; ++t) a1[t] = zero4;
    const u16* wp1 = w1f + (oc * 4 + wave) * 4 * 512 + lane * 8;
    #pragma unroll
    for (int ks = 0; ks < 4; ++ks) {
      const bf16x8 bfr = *(const bf16x8*)(wp1 + ks * 512);
      #pragma unroll
      for (int ti = 0; ti < 4; ++ti) {
        const bf16x8 afr = *(const bf16x8*)(xn + (ti * 16 + l15) * 136 + ks * 32 + lg * 8);
        a1[ti] = __builtin_amdgcn_mfma_f32_16x16x32_bf16(afr, bfr, a1[ti], 0, 0, 0);
      }
    }
    // prefetch w2 fragments for this oc (independent of h1c; hides under GELU+barrier)
    bf16x8 w2r[2][2];
    #pragma unroll
    for (int tj = 0; tj < 2; ++tj)
      #pragma unroll
      for (int ks = 0; ks < 2; ++ks)
        w2r[tj][ks] = *(const bf16x8*)(w2f + (((wave * 2 + tj) * 16) + (oc * 2 + ks)) * 512 + lane * 8);

    const int ol = wave * 16 + l15;
    const float b1v = b1[oc * 64 + ol];
    #pragma unroll
    for (int ti = 0; ti < 4; ++ti) {
      #pragma unroll
      for (int r = 0; r < 4; ++r) {
        const int tok = ti * 16 + lg * 4 + r;
        const float u = a1[ti][r] + b1v;
        // tanh-GELU: u * sigmoid(1.5957691*(u + 0.044715 u^3)); |err| < ~1e-3
        const float t = u + 0.044715f * u * u * u;
        const float ge = u / (1.0f + __expf(-1.5957691216057308f * t));
        h1c[tok * 72 + ol] = f2bf(ge);
      }
    }
    __syncthreads();

    // h2 accumulate with prefetched w2 fragments
    #pragma unroll
    for (int ks = 0; ks < 2; ++ks) {
      bf16x8 afr[4];
      #pragma unroll
      for (int ti = 0; ti < 4; ++ti)
        afr[ti] = *(const bf16x8*)(h1c + (ti * 16 + l15) * 72 + ks * 32 + lg * 8);
      #pragma unroll
      for (int ti = 0; ti < 4; ++ti)
        #pragma unroll
        for (int tj = 0; tj < 2; ++tj)
          acc2[ti][tj] = __builtin_amdgcn_mfma_f32_16x16x32_bf16(afr[ti], w2r[tj][ks], acc2[ti][tj], 0, 0, 0);
    }
  }

  // ---- epilogue: out = x1 + 0.5*(h2 + b2) ----
  #pragma unroll
  for (int tj = 0; tj < 2; ++tj) {
    const int c = wave * 32 + tj * 16 + l15;
    const float b2v = b2[c];
    #pragma unroll
    for (int ti = 0; ti < 4; ++ti) {
      #pragma unroll
      for (int r = 0; r < 4; ++r) {
        const int tokg = base + ti * 16 + lg * 4 + r;
        out[tokg * 128 + c] += 0.5f * (acc2[ti][tj][r] + b2v);
      }
    }
  }
}

extern "C" void kernel_launch(void* const* d_in, const int* in_sizes, int n_in,
                              void* d_out, int out_size, void* d_ws, size_t ws_size,
                              hipStream_t stream) {
  const float* x      = (const float*)d_in[0];
  const float* qkv_w  = (const float*)d_in[1];
  const float* rpb    = (const float*)d_in[2];
  const float* proj_w = (const float*)d_in[3];
  const float* proj_b = (const float*)d_in[4];
  const float* n1g    = (const float*)d_in[5];
  const float* n1b    = (const float*)d_in[6];
  const float* n2g    = (const float*)d_in[7];
  const float* n2b    = (const float*)d_in[8];
  const float* w1     = (const float*)d_in[9];
  const float* b1     = (const float*)d_in[10];
  const float* w2     = (const float*)d_in[11];
  const float* b2     = (const float*)d_in[12];
  const float* amask  = (const float*)d_in[13];
  const int*   rel    = (const int*)d_in[14];
  float* out  = (float*)d_out;

  unsigned char* ws = (unsigned char*)d_ws;
  float* bias = (float*)(ws);               // 64KB
  u16* qkv_f  = (u16*)(ws + 65536);         // 96KB
  u16* proj_f = (u16*)(ws + 163840);        // 32KB
  u16* w1f    = (u16*)(ws + 196608);        // 128KB
  u16* w2f    = (u16*)(ws + 327680);        // 128KB

  prep_kernel<<<256, 256, 0, stream>>>(rpb, rel, qkv_w, proj_w, w1, w2,
                                       bias, qkv_f, proj_f, w1f, w2f);
  attn_kernel<<<2048, 512, 0, stream>>>(x, qkv_f, proj_f, proj_b, n1g, n1b, amask, bias, out);
  mlp_kernel<<<2048, 256, 0, stream>>>(w1f, b1, w2f, b2, n2g, n2b, out);
}